// Round 6
// baseline (1978.223 us; speedup 1.0000x reference)
//
#include <hip/hip_runtime.h>
#include <hip/hip_bf16.h>
#include <math.h>

// EABlock, MFMA bf16 2-term-split implementation.
// Shapes: B=32, C=128, IC=256, NH=8, H=W=64 (HW=4096), HID=512.
//
// GEMM work uses v_mfma_f32_16x16x32_bf16. Weights are split hi+lo bf16
// (A operand, 2 MFMA per pair -> fp32-grade weight precision); activations
// are plain bf16 (B operand, single LDS plane). Weights are pre-swizzled by
// prep_b into per-wave fragment blocks (1KB contiguous per frag; lane loads
// base+lane*16, coalesced). mid (conv1->conv2) is NCHW bf16-PAIR planes:
// u32 plane q holds channels {2q,2q+1} packed lo/hi -> conv1 epilogue writes
// are fully-coalesced u32 stores (64B lines fully written, no RFO), conv2
// staging is 4 coalesced u32 plane-loads with zero unpack VALU.
// Conv A-frags are double-buffer prefetched across the 9 taps.

#define Bn 32
#define Cn 128
#define ICn 256
#define NHn 8
#define HWn 4096
#define HIDn 512
#define GPAD 40

typedef __bf16 bf16x8 __attribute__((ext_vector_type(8)));
typedef float f32x4 __attribute__((ext_vector_type(4)));

__device__ __forceinline__ uint32_t bf16r(float v) {
  uint32_t u = __float_as_uint(v);
  return (u + 0x7FFFu + ((u >> 16) & 1u)) >> 16;  // RNE to bf16 bits
}
__device__ __forceinline__ void split_bf16(float v, uint32_t& h, uint32_t& l) {
  h = bf16r(v);
  float rem = v - __uint_as_float(h << 16);
  l = bf16r(rem);
}
__device__ __forceinline__ uint4 pack8(const float* v) {
  uint32_t w[4];
#pragma unroll
  for (int q = 0; q < 4; ++q)
    w[q] = bf16r(v[2 * q]) | (bf16r(v[2 * q + 1]) << 16);
  return make_uint4(w[0], w[1], w[2], w[3]);
}
#define MFMA(a, b, c) __builtin_amdgcn_mfma_f32_16x16x32_bf16((a), (b), (c), 0, 0, 0)

// ---------------------------------------------------------------- prep ----
__global__ __launch_bounds__(256) void prep_a_kernel(
    const float* __restrict__ bn1_g, const float* __restrict__ bn1_b,
    const float* __restrict__ bn1_m, const float* __restrict__ bn1_v,
    const float* __restrict__ kmat,
    const float* __restrict__ bn2_g, const float* __restrict__ bn2_b,
    const float* __restrict__ bn2_m, const float* __restrict__ bn2_v,
    float* __restrict__ keff, float* __restrict__ biask,
    float* __restrict__ inv2, float* __restrict__ beta2) {
  __shared__ float sinv1[Cn], sbeta1[Cn];
  const int t = threadIdx.x;  // 256
  if (t < Cn) {
    float i1 = bn1_g[t] / sqrtf(bn1_v[t] + 1e-5f);
    sinv1[t] = i1;
    sbeta1[t] = bn1_b[t] - bn1_m[t] * i1;
    float i2 = bn2_g[t] / sqrtf(bn2_v[t] + 1e-6f);
    inv2[t] = i2;
    beta2[t] = bn2_b[t] - bn2_m[t] * i2;
  }
  __syncthreads();
  float bk = 0.f;  // t = output channel o in [0,256)
  for (int c = 0; c < Cn; ++c) {
    float kv = kmat[t * Cn + c];
    keff[t * Cn + c] = kv * sinv1[c];
    bk += kv * sbeta1[c];
  }
  biask[t] = bk;
}

// Re-lay weights into per-wave fragment blocks (split hi/lo planes).
// dest d: e=d&7, lane=(d>>3)&63, f=d>>9; f=(tap*NOB+ob)*NIB+ib;
// oc=ob*16+(lane&15), k=ib*32+(lane>>4)*8+e.
__global__ __launch_bounds__(256) void prep_b_kernel(
    const float* __restrict__ keff, const float* __restrict__ vmat,
    const float* __restrict__ w1, const float* __restrict__ w2,
    ushort* __restrict__ k1h, ushort* __restrict__ k1l,
    ushort* __restrict__ vh, ushort* __restrict__ vl,
    ushort* __restrict__ wt1h, ushort* __restrict__ wt1l,
    ushort* __restrict__ wt2h, ushort* __restrict__ wt2l) {
  const int stride = gridDim.x * blockDim.x;
  const int tid0 = blockIdx.x * blockDim.x + threadIdx.x;
  uint32_t h, l;
  // k1: M=256 (NOB=16), K=128 (NIB=4), 1 tap
  for (int d = tid0; d < ICn * Cn; d += stride) {
    int e = d & 7, lane = (d >> 3) & 63, f = d >> 9;
    int ib = f & 3, ob = f >> 2;
    int oc = ob * 16 + (lane & 15), k = ib * 32 + (lane >> 4) * 8 + e;
    split_bf16(keff[oc * Cn + k], h, l);
    k1h[d] = (ushort)h; k1l[d] = (ushort)l;
  }
  // v: M=128 (NOB=8), K=256 (NIB=8), 1 tap
  for (int d = tid0; d < Cn * ICn; d += stride) {
    int e = d & 7, lane = (d >> 3) & 63, f = d >> 9;
    int ib = f & 7, ob = f >> 3;
    int oc = ob * 16 + (lane & 15), k = ib * 32 + (lane >> 4) * 8 + e;
    split_bf16(vmat[oc * ICn + k], h, l);
    vh[d] = (ushort)h; vl[d] = (ushort)l;
  }
  // wt1: 9 taps, M=512 (NOB=32), K=128 (NIB=4)
  for (int d = tid0; d < 9 * HIDn * Cn; d += stride) {
    int e = d & 7, lane = (d >> 3) & 63, f = d >> 9;
    int ib = f & 3, obt = f >> 2;
    int ob = obt & 31, tap = obt >> 5;
    int oc = ob * 16 + (lane & 15), k = ib * 32 + (lane >> 4) * 8 + e;
    split_bf16(w1[(oc * Cn + k) * 9 + tap], h, l);
    wt1h[d] = (ushort)h; wt1l[d] = (ushort)l;
  }
  // wt2: 9 taps, M=128 (NOB=8), K=512 (NIB=16)
  for (int d = tid0; d < 9 * Cn * HIDn; d += stride) {
    int e = d & 7, lane = (d >> 3) & 63, f = d >> 9;
    int ib = f & 15, obt = f >> 4;
    int ob = obt & 7, tap = obt >> 3;
    int oc = ob * 16 + (lane & 15), k = ib * 32 + (lane >> 4) * 8 + e;
    split_bf16(w2[(oc * HIDn + k) * 9 + tap], h, l);
    wt2h[d] = (ushort)h; wt2l[d] = (ushort)l;
  }
}

// ------------------------------------------------------------- gemm1 ------
// S[bz,o,p] = biask[o] + sum_c keff[o,c]*x[b0+bz,c,p].  M=256,N=4096,K=128.
__global__ __launch_bounds__(256, 4) void gemm1_mfma(
    const float* __restrict__ x, const ushort* __restrict__ k1h,
    const ushort* __restrict__ k1l, const float* __restrict__ biask,
    float* __restrict__ S, int b0) {
  const int tid = threadIdx.x, lane = tid & 63, wave = tid >> 6;
  const int wm = wave >> 1, wn = wave & 1;
  const int l15 = lane & 15, lg = lane >> 4;
  const int p0 = blockIdx.x * 128;
  const int oc0 = blockIdx.y * 128;
  const int bg = b0 + blockIdx.z;
  __shared__ __align__(16) ushort Xb[128 * GPAD];  // 10 KB
  f32x4 acc[4][4] = {};
  for (int c0 = 0; c0 < Cn; c0 += 32) {
    __syncthreads();
    for (int i = tid; i < 512; i += 256) {
      int p = i & 127, g = i >> 7;
      const float* src = x + ((size_t)bg * Cn + c0 + g * 8) * HWn + p0 + p;
      float v[8];
#pragma unroll
      for (int j = 0; j < 8; ++j) v[j] = src[(size_t)j * HWn];
      *(uint4*)&Xb[p * GPAD + g * 8] = pack8(v);
    }
    __syncthreads();
    bf16x8 Bf[4];
#pragma unroll
    for (int nf = 0; nf < 4; ++nf)
      Bf[nf] = *(const bf16x8*)&Xb[(wn * 64 + nf * 16 + l15) * GPAD + lg * 8];
#pragma unroll
    for (int mf = 0; mf < 4; ++mf) {
      int fidx = ((oc0 >> 4) + wm * 4 + mf) * 4 + (c0 >> 5);
      bf16x8 Ah = *(const bf16x8*)(k1h + (size_t)fidx * 512 + lane * 8);
      bf16x8 Al = *(const bf16x8*)(k1l + (size_t)fidx * 512 + lane * 8);
#pragma unroll
      for (int nf = 0; nf < 4; ++nf)
        acc[mf][nf] = MFMA(Al, Bf[nf], MFMA(Ah, Bf[nf], acc[mf][nf]));
    }
  }
#pragma unroll
  for (int mf = 0; mf < 4; ++mf)
#pragma unroll
    for (int r = 0; r < 4; ++r) {
      int oc = oc0 + wm * 64 + mf * 16 + lg * 4 + r;
      float bk = biask[oc];
#pragma unroll
      for (int nf = 0; nf < 4; ++nf) {
        int p = p0 + wn * 64 + nf * 16 + l15;
        S[((size_t)blockIdx.z * ICn + oc) * HWn + p] = acc[mf][nf][r] + bk;
      }
    }
}

// ----------------------------------------------------------- softmax ------
__global__ __launch_bounds__(256) void softmax_kernel(float* __restrict__ S) {
  __shared__ float row[HWn];
  __shared__ float red[4];
  const int t = threadIdx.x;
  float4* rowv = (float4*)row;
  float4* Sv = (float4*)(S + (size_t)blockIdx.x * HWn);
  float lmax = -1e30f;
#pragma unroll
  for (int i = 0; i < 4; ++i) {
    float4 v = Sv[t + 256 * i];
    rowv[t + 256 * i] = v;
    lmax = fmaxf(lmax, fmaxf(fmaxf(v.x, v.y), fmaxf(v.z, v.w)));
  }
#pragma unroll
  for (int off = 32; off; off >>= 1) lmax = fmaxf(lmax, __shfl_xor(lmax, off));
  if ((t & 63) == 0) red[t >> 6] = lmax;
  __syncthreads();
  lmax = fmaxf(fmaxf(red[0], red[1]), fmaxf(red[2], red[3]));
  float lsum = 0.f;
#pragma unroll
  for (int i = 0; i < 4; ++i) {
    float4 v = rowv[t + 256 * i];
    v.x = expf(v.x - lmax); v.y = expf(v.y - lmax);
    v.z = expf(v.z - lmax); v.w = expf(v.w - lmax);
    rowv[t + 256 * i] = v;
    lsum += v.x + v.y + v.z + v.w;
  }
#pragma unroll
  for (int off = 32; off; off >>= 1) lsum += __shfl_xor(lsum, off);
  __syncthreads();
  if ((t & 63) == 0) red[t >> 6] = lsum;
  __syncthreads();
  lsum = red[0] + red[1] + red[2] + red[3];
  float inv = 1.0f / lsum;
#pragma unroll
  for (int i = 0; i < 4; ++i) {
    float4 v = rowv[t + 256 * i];
    v.x *= inv; v.y *= inv; v.z *= inv; v.w *= inv;
    Sv[t + 256 * i] = v;
  }
}

// -------------------------------------------------------------- hsum ------
__global__ __launch_bounds__(256) void hsum_kernel(const float* __restrict__ S,
                                                   float* __restrict__ hsum) {
  const int p4 = blockIdx.x * 256 + threadIdx.x;
  const int hh = blockIdx.y, bz = blockIdx.z;
  const float* base = S + ((size_t)bz * ICn + hh * 32) * HWn;
  float4 a = make_float4(0.f, 0.f, 0.f, 0.f);
#pragma unroll
  for (int i = 0; i < 32; ++i) {
    float4 v = ((const float4*)(base + (size_t)i * HWn))[p4];
    a.x += v.x; a.y += v.y; a.z += v.z; a.w += v.w;
  }
  ((float4*)(hsum + ((size_t)bz * NHn + hh) * HWn))[p4] = a;
}

// ------------------------------------------------------------- gemm2 ------
// x2[bg,c,p] = x[bg,c,p] + sum_o vmat[c,o]*(S[bz,o,p]*rr[bz,head,p]).
__global__ __launch_bounds__(256, 4) void gemm2_mfma(
    const float* __restrict__ S, const ushort* __restrict__ vh,
    const ushort* __restrict__ vl, const float* __restrict__ hsum,
    const float* __restrict__ x, float* __restrict__ x2, int b0) {
  const int tid = threadIdx.x, lane = tid & 63, wave = tid >> 6;
  const int wm = wave >> 1, wn = wave & 1;
  const int l15 = lane & 15, lg = lane >> 4;
  const int p0 = blockIdx.x * 128;
  const int bz = blockIdx.z, bg = b0 + bz;
  __shared__ __align__(16) ushort Xb[128 * GPAD];
  f32x4 acc[4][4] = {};
  for (int hh = 0; hh < NHn; ++hh) {  // K chunk == head (32 o-rows)
    __syncthreads();
    for (int i = tid; i < 512; i += 256) {
      int p = i & 127, g = i >> 7;
      const float* src = S + ((size_t)bz * ICn + hh * 32 + g * 8) * HWn + p0 + p;
      float rr = 1.0f / (hsum[((size_t)bz * NHn + hh) * HWn + p0 + p] + 1e-6f);
      float v[8];
#pragma unroll
      for (int j = 0; j < 8; ++j) v[j] = src[(size_t)j * HWn] * rr;
      *(uint4*)&Xb[p * GPAD + g * 8] = pack8(v);
    }
    __syncthreads();
    bf16x8 Bf[4];
#pragma unroll
    for (int nf = 0; nf < 4; ++nf)
      Bf[nf] = *(const bf16x8*)&Xb[(wn * 64 + nf * 16 + l15) * GPAD + lg * 8];
#pragma unroll
    for (int mf = 0; mf < 4; ++mf) {
      int fidx = (wm * 4 + mf) * 8 + hh;
      bf16x8 Ah = *(const bf16x8*)(vh + (size_t)fidx * 512 + lane * 8);
      bf16x8 Al = *(const bf16x8*)(vl + (size_t)fidx * 512 + lane * 8);
#pragma unroll
      for (int nf = 0; nf < 4; ++nf)
        acc[mf][nf] = MFMA(Al, Bf[nf], MFMA(Ah, Bf[nf], acc[mf][nf]));
    }
  }
#pragma unroll
  for (int mf = 0; mf < 4; ++mf)
#pragma unroll
    for (int r = 0; r < 4; ++r) {
      int c = wm * 64 + mf * 16 + lg * 4 + r;
#pragma unroll
      for (int nf = 0; nf < 4; ++nf) {
        int p = p0 + wn * 64 + nf * 16 + l15;
        size_t off = ((size_t)bg * Cn + c) * HWn + p;
        x2[off] = x[off] + acc[mf][nf][r];
      }
    }
}

// ------------------------------------------------------------ conv3x3 -----
// Implicit-GEMM 3x3 SAME conv, 128oc x 128p tile (2 rows x 64 cols).
// B: haloed LDS [4 rows][66 cols][40-pad ic], single bf16 plane; 9 taps =
// 9 shifted reads. A: pre-swizzled weight frags from global/L2, double-buffer
// prefetched one tap ahead (tap0 issued under the staging barrier).
// conv1: fp32 NCHW in + BN at staging (in-bounds only), GELU epilogue ->
// NCHW bf16-PAIR mid (coalesced u32 stores). conv2: PAIR input (4 coalesced
// u32 plane loads, no unpack), f32 residual epilogue.
template <int IN_C, int OUT_C, bool IN_PAIRED, bool DO_BN, bool GELU_PAIR,
          bool DO_RESID, bool IN_ABS, bool OUT_ABS>
__global__ __launch_bounds__(256, 3) void conv_mfma(
    const void* __restrict__ in_v, const ushort* __restrict__ wth,
    const ushort* __restrict__ wtl, const float* __restrict__ bias,
    const float* __restrict__ inv2, const float* __restrict__ beta2,
    const float* __restrict__ resid, void* __restrict__ out_v, int b0) {
  constexpr int NOB = OUT_C / 16, NIB = IN_C / 32;
  const int tid = threadIdx.x, lane = tid & 63, wave = tid >> 6;
  const int wm = wave >> 1, wn = wave & 1;
  const int l15 = lane & 15, lg = lane >> 4;
  const int p0 = blockIdx.x * 128;
  const int y0 = p0 >> 6;  // two output rows y0, y0+1
  const int oc0 = blockIdx.y * 128;
  const int bz = blockIdx.z;
  const int bin = IN_ABS ? (b0 + bz) : bz;
  const int bout = OUT_ABS ? (b0 + bz) : bz;
  __shared__ __align__(16) ushort Xb[4 * 66 * GPAD];  // 21.1 KB
  f32x4 acc[4][4] = {};
  bf16x8 A0h[4], A0l[4], A1h[4], A1l[4];

  for (int ic0 = 0; ic0 < IN_C; ic0 += 32) {
    __syncthreads();
    for (int i = tid; i < 4 * 66 * 4; i += 256) {
      int c = i % 66;
      int rg = i / 66;
      int r = rg & 3, g = rg >> 2;
      int gy = y0 - 1 + r, gx = c - 1;
      bool inb = (gy >= 0 && gy < 64 && gx >= 0 && gx < 64);
      uint4 w = make_uint4(0u, 0u, 0u, 0u);
      if constexpr (IN_PAIRED) {
        const uint32_t* src = (const uint32_t*)in_v +
                              ((size_t)bin * (IN_C / 2) + (ic0 >> 1) + g * 4) *
                                  HWn +
                              gy * 64 + gx;
        if (inb) {
          w.x = src[0 * HWn];
          w.y = src[1 * HWn];
          w.z = src[2 * HWn];
          w.w = src[3 * HWn];
        }
      } else {
        float v[8] = {};
        if (inb) {
          const float* src = (const float*)in_v +
                             ((size_t)bin * IN_C + ic0 + g * 8) * HWn +
                             gy * 64 + gx;
#pragma unroll
          for (int j = 0; j < 8; ++j) {
            float val = src[(size_t)j * HWn];
            if constexpr (DO_BN)
              val = val * inv2[ic0 + g * 8 + j] + beta2[ic0 + g * 8 + j];
            v[j] = val;
          }
        }
        w = pack8(v);
      }
      *(uint4*)&Xb[(r * 66 + c) * GPAD + g * 8] = w;
    }

    // issue tap-0 A-frag loads; latency hides under the barrier.
    auto loadA = [&](bf16x8* Dh, bf16x8* Dl, int tap) {
#pragma unroll
      for (int mf = 0; mf < 4; ++mf) {
        size_t f =
            ((size_t)(tap * NOB + (oc0 >> 4) + wm * 4 + mf)) * NIB + (ic0 >> 5);
        Dh[mf] = *(const bf16x8*)(wth + f * 512 + lane * 8);
        Dl[mf] = *(const bf16x8*)(wtl + f * 512 + lane * 8);
      }
    };
    loadA(A0h, A0l, 0);
    __syncthreads();

#pragma unroll
    for (int tap = 0; tap < 9; ++tap) {
      bf16x8* curh = (tap & 1) ? A1h : A0h;
      bf16x8* curl = (tap & 1) ? A1l : A0l;
      bf16x8* nxth = (tap & 1) ? A0h : A1h;
      bf16x8* nxtl = (tap & 1) ? A0l : A1l;
      if (tap < 8) loadA(nxth, nxtl, tap + 1);  // prefetch next tap
      const int kh = tap / 3, kw = tap % 3;
      bf16x8 Bf[4];
#pragma unroll
      for (int nf = 0; nf < 4; ++nf) {
        int n = wn * 64 + nf * 16 + l15;
        int addr = (((n >> 6) + kh) * 66 + (n & 63) + kw) * GPAD + lg * 8;
        Bf[nf] = *(const bf16x8*)&Xb[addr];
      }
#pragma unroll
      for (int mf = 0; mf < 4; ++mf)
#pragma unroll
        for (int nf = 0; nf < 4; ++nf)
          acc[mf][nf] = MFMA(curl[mf], Bf[nf], MFMA(curh[mf], Bf[nf], acc[mf][nf]));
    }
  }

  if constexpr (GELU_PAIR) {
    // NCHW bf16-pair output: plane q = channels {2q,2q+1}; u32 stores,
    // 16 consecutive lanes -> 64B fully-written lines.
    uint32_t* outp = (uint32_t*)out_v;
#pragma unroll
    for (int mf = 0; mf < 4; ++mf) {
      int ocb = oc0 + wm * 64 + mf * 16 + lg * 4;  // multiple of 4
#pragma unroll
      for (int nf = 0; nf < 4; ++nf) {
        int n = wn * 64 + nf * 16 + l15;
        float g0, g1;
        size_t base = ((size_t)bout * (OUT_C / 2) + (ocb >> 1)) * HWn + p0 + n;
        g0 = acc[mf][nf][0] + bias[ocb + 0];
        g0 = 0.5f * g0 * (1.f + erff(g0 * 0.70710678118654752f));
        g1 = acc[mf][nf][1] + bias[ocb + 1];
        g1 = 0.5f * g1 * (1.f + erff(g1 * 0.70710678118654752f));
        outp[base] = bf16r(g0) | (bf16r(g1) << 16);
        g0 = acc[mf][nf][2] + bias[ocb + 2];
        g0 = 0.5f * g0 * (1.f + erff(g0 * 0.70710678118654752f));
        g1 = acc[mf][nf][3] + bias[ocb + 3];
        g1 = 0.5f * g1 * (1.f + erff(g1 * 0.70710678118654752f));
        outp[base + HWn] = bf16r(g0) | (bf16r(g1) << 16);
      }
    }
  } else {
#pragma unroll
    for (int mf = 0; mf < 4; ++mf)
#pragma unroll
      for (int r = 0; r < 4; ++r) {
        int oc = oc0 + wm * 64 + mf * 16 + lg * 4 + r;
        float bv = bias[oc];
#pragma unroll
        for (int nf = 0; nf < 4; ++nf) {
          int n = wn * 64 + nf * 16 + l15;
          size_t off = ((size_t)bout * OUT_C + oc) * HWn + p0 + n;
          float vv = acc[mf][nf][r] + bv;
          if constexpr (DO_RESID) vv += resid[off];
          ((float*)out_v)[off] = vv;
        }
      }
  }
}

// ----------------------------------------------------------------------- //
extern "C" void kernel_launch(void* const* d_in, const int* in_sizes, int n_in,
                              void* d_out, int out_size, void* d_ws,
                              size_t ws_size, hipStream_t stream) {
  const float* x = (const float*)d_in[0];
  const float* bn1_g = (const float*)d_in[1];
  const float* bn1_b = (const float*)d_in[2];
  const float* bn1_m = (const float*)d_in[3];
  const float* bn1_v = (const float*)d_in[4];
  const float* kmat = (const float*)d_in[5];
  const float* vmat = (const float*)d_in[6];
  const float* bn2_g = (const float*)d_in[7];
  const float* bn2_b = (const float*)d_in[8];
  const float* bn2_m = (const float*)d_in[9];
  const float* bn2_v = (const float*)d_in[10];
  const float* w1 = (const float*)d_in[11];
  const float* b1 = (const float*)d_in[12];
  const float* w2 = (const float*)d_in[13];
  const float* b2 = (const float*)d_in[14];
  float* out = (float*)d_out;

  // ---- workspace carve (bytes; every chunk 512B-aligned) ----
  char* p = (char*)d_ws;
  float* keff = (float*)p;   p += (size_t)ICn * Cn * 4;
  float* biask = (float*)p;  p += 1024;
  float* inv2 = (float*)p;   p += 512;
  float* beta2 = (float*)p;  p += 512;
  ushort* k1h = (ushort*)p;  p += (size_t)ICn * Cn * 2;
  ushort* k1l = (ushort*)p;  p += (size_t)ICn * Cn * 2;
  ushort* vh = (ushort*)p;   p += (size_t)Cn * ICn * 2;
  ushort* vl = (ushort*)p;   p += (size_t)Cn * ICn * 2;
  ushort* wt1h = (ushort*)p; p += (size_t)9 * HIDn * Cn * 2;
  ushort* wt1l = (ushort*)p; p += (size_t)9 * HIDn * Cn * 2;
  ushort* wt2h = (ushort*)p; p += (size_t)9 * Cn * HIDn * 2;
  ushort* wt2l = (ushort*)p; p += (size_t)9 * Cn * HIDn * 2;
  size_t const_bytes = (size_t)(p - (char*)d_ws);

  // per-sample: S fp32 [256][4096] = 4MB; mid pair-u32 [256][4096] = 4MB.
  const size_t SM_BYTES = (size_t)ICn * HWn * 4;
  const size_t HS_BYTES = (size_t)NHn * HWn * 4;
  int bc = 32;
  while (bc > 1 && const_bytes + (size_t)bc * (SM_BYTES + HS_BYTES) > ws_size)
    bc >>= 1;
  float* S = (float*)p;        // S dead before conv1 writes mid (same region)
  uint32_t* mid = (uint32_t*)p;  // NCHW bf16-pair planes
  float* hsum = (float*)(p + (size_t)bc * SM_BYTES);
  float* x2 = out;  // x2 lives in d_out; conv2 finalizes in-place

  prep_a_kernel<<<dim3(1), dim3(256), 0, stream>>>(
      bn1_g, bn1_b, bn1_m, bn1_v, kmat, bn2_g, bn2_b, bn2_m, bn2_v, keff,
      biask, inv2, beta2);
  prep_b_kernel<<<dim3(1024), dim3(256), 0, stream>>>(
      keff, vmat, w1, w2, k1h, k1l, vh, vl, wt1h, wt1l, wt2h, wt2l);

  for (int b0 = 0; b0 < Bn; b0 += bc) {
    gemm1_mfma<<<dim3(32, 2, bc), dim3(256), 0, stream>>>(x, k1h, k1l, biask,
                                                          S, b0);
    softmax_kernel<<<dim3(bc * ICn), dim3(256), 0, stream>>>(S);
    hsum_kernel<<<dim3(4, NHn, bc), dim3(256), 0, stream>>>(S, hsum);
    gemm2_mfma<<<dim3(32, 1, bc), dim3(256), 0, stream>>>(S, vh, vl, hsum, x,
                                                          x2, b0);
    conv_mfma<Cn, HIDn, false, true, true, false, true, false>
        <<<dim3(32, 4, bc), dim3(256), 0, stream>>>(x2, wt1h, wt1l, b1, inv2,
                                                    beta2, nullptr, mid, b0);
    conv_mfma<HIDn, Cn, true, false, false, true, false, true>
        <<<dim3(32, 1, bc), dim3(256), 0, stream>>>(mid, wt2h, wt2l, b2,
                                                    nullptr, nullptr, x2, out,
                                                    b0);
  }
}